// Round 5
// baseline (218.142 us; speedup 1.0000x reference)
//
#include <hip/hip_runtime.h>

#define EPS 1e-8f
#define BLOCK 256
#define GPT 2                  // gaussians per thread
#define TILE (BLOCK * GPT)     // 512 gaussians per block

typedef float fvec4 __attribute__((ext_vector_type(4)));

__global__ __launch_bounds__(BLOCK) void gaussians_cov_kernel(
    const fvec4* __restrict__ quat,
    const float* __restrict__ scale,
    fvec4*       __restrict__ out4,     // out (N,9) viewed as fvec4 stream
    int n)
{
    __shared__ float s_out[TILE * 9];   // 18 KB -> 8 blocks/CU, full occupancy

    const int t    = threadIdx.x;
    const int base = blockIdx.x * TILE;

    // two gaussians per thread, BLOCK apart so each wave's loads stay contiguous
    #pragma unroll
    for (int g = 0; g < GPT; ++g) {
        const int lt = t + g * BLOCK;   // local index in tile
        const int i  = base + lt;
        if (i < n) {
            fvec4 q = __builtin_nontemporal_load(&quat[i]);   // 16 B/lane coalesced
            float w = q.x, x = q.y, y = q.z, z = q.w;

            // R is quadratic in normalized q: fold normalization into t2 = 2/|q|^2.
            float n2 = w*w + x*x + y*y + z*z;
            float t2 = 2.0f / n2;

            float xx = x*x*t2, yy = y*y*t2, zz = z*z*t2;
            float xy = x*y*t2, xz = x*z*t2, yz = y*z*t2;
            float wx = w*x*t2, wy = w*y*t2, wz = w*z*t2;

            float r00 = 1.0f - yy - zz, r01 = xy - wz,        r02 = xz + wy;
            float r10 = xy + wz,        r11 = 1.0f - xx - zz, r12 = yz - wx;
            float r20 = xz - wy,        r21 = yz + wx,        r22 = 1.0f - xx - yy;

            // direct global reads: 3 lines/wave, each touched once (L1 serves)
            float s0 = fabsf(__builtin_nontemporal_load(&scale[3*i + 0])) + EPS;
            float s1 = fabsf(__builtin_nontemporal_load(&scale[3*i + 1])) + EPS;
            float s2 = fabsf(__builtin_nontemporal_load(&scale[3*i + 2])) + EPS;
            float a = s0*s0, b = s1*s1, c = s2*s2;

            // M = R diag(s^2) R^T, symmetric
            float m00 = r00*r00*a + r01*r01*b + r02*r02*c;
            float m01 = r00*r10*a + r01*r11*b + r02*r12*c;
            float m02 = r00*r20*a + r01*r21*b + r02*r22*c;
            float m11 = r10*r10*a + r11*r11*b + r12*r12*c;
            float m12 = r10*r20*a + r11*r21*b + r12*r22*c;
            float m22 = r20*r20*a + r21*r21*b + r22*r22*c;

            float* o = s_out + 9*lt;    // stride-9 LDS writes: 2 lanes/bank, free
            o[0] = m00; o[1] = m01; o[2] = m02;
            o[3] = m01; o[4] = m11; o[5] = m12;
            o[6] = m02; o[7] = m12; o[8] = m22;
        }
    }
    __syncthreads();

    // cooperative coalesced nt-store flush: 1152 fvec4 per block
    {
        const int obase4 = blockIdx.x * (TILE * 9 / 4);
        const long long otot4 = (9LL * n) / 4;
        #pragma unroll
        for (int j = t; j < TILE * 9 / 4; j += BLOCK) {
            long long go = obase4 + (long long)j;
            if (go < otot4)
                __builtin_nontemporal_store(((fvec4*)s_out)[j], &out4[go]);
        }
    }
}

extern "C" void kernel_launch(void* const* d_in, const int* in_sizes, int n_in,
                              void* d_out, int out_size, void* d_ws, size_t ws_size,
                              hipStream_t stream) {
    const fvec4* quat  = (const fvec4*)d_in[0];
    const float* scale = (const float*)d_in[1];
    fvec4* out4 = (fvec4*)d_out;
    int n = in_sizes[0] / 4;   // quaternion is (N,4)

    int grid = (n + TILE - 1) / TILE;
    gaussians_cov_kernel<<<grid, BLOCK, 0, stream>>>(quat, scale, out4, n);
}

// Round 6
// 217.450 us; speedup vs baseline: 1.0032x; 1.0032x over previous
//
#include <hip/hip_runtime.h>

#define EPS 1e-8f
#define BLOCK 512
#define GPT 2                   // gaussians per thread
#define TILE (BLOCK * GPT)      // 1024 gaussians per block

typedef float fvec4 __attribute__((ext_vector_type(4)));

__global__ __launch_bounds__(BLOCK) void gaussians_cov_kernel(
    const fvec4* __restrict__ quat,
    const fvec4* __restrict__ scale4,   // scale (N,3) viewed as fvec4 stream
    fvec4*       __restrict__ out4,     // out (N,9) viewed as fvec4 stream
    int n)
{
    __shared__ float s_scale[TILE * 3];  // 12 KB
    __shared__ float s_out[TILE * 9];    // 36 KB  (48 KB total -> 3 blocks/CU)

    const int t    = threadIdx.x;
    const int base = blockIdx.x * TILE;

    // ---- cooperative coalesced nt-load of the scale tile (768 fvec4 / block) ----
    {
        const int sbase4 = blockIdx.x * (TILE * 3 / 4);
        const int stot4  = (3 * n) / 4;
        #pragma unroll
        for (int j = t; j < TILE * 3 / 4; j += BLOCK) {
            int gi = sbase4 + j;
            if (gi < stot4)
                ((fvec4*)s_scale)[j] = __builtin_nontemporal_load(&scale4[gi]);
        }
    }

    // ---- issue both quat loads up front (MLP), then compute ----
    fvec4 q[GPT];
    #pragma unroll
    for (int g = 0; g < GPT; ++g) {
        int i = base + t + g * BLOCK;
        if (i < n) q[g] = __builtin_nontemporal_load(&quat[i]);
    }

    __syncthreads();   // scale tile ready

    #pragma unroll
    for (int g = 0; g < GPT; ++g) {
        const int lt = t + g * BLOCK;
        const int i  = base + lt;
        if (i < n) {
            float w = q[g].x, x = q[g].y, y = q[g].z, z = q[g].w;

            // R is quadratic in normalized q: fold normalization into t2 = 2/|q|^2.
            float n2 = w*w + x*x + y*y + z*z;
            float t2 = 2.0f / n2;

            float xx = x*x*t2, yy = y*y*t2, zz = z*z*t2;
            float xy = x*y*t2, xz = x*z*t2, yz = y*z*t2;
            float wx = w*x*t2, wy = w*y*t2, wz = w*z*t2;

            float r00 = 1.0f - yy - zz, r01 = xy - wz,        r02 = xz + wy;
            float r10 = xy + wz,        r11 = 1.0f - xx - zz, r12 = yz - wx;
            float r20 = xz - wy,        r21 = yz + wx,        r22 = 1.0f - xx - yy;

            float s0 = fabsf(s_scale[3*lt + 0]) + EPS;   // stride-3 LDS: 2 lanes/bank, free
            float s1 = fabsf(s_scale[3*lt + 1]) + EPS;
            float s2 = fabsf(s_scale[3*lt + 2]) + EPS;
            float a = s0*s0, b = s1*s1, c = s2*s2;

            // M = R diag(s^2) R^T, symmetric
            float m00 = r00*r00*a + r01*r01*b + r02*r02*c;
            float m01 = r00*r10*a + r01*r11*b + r02*r12*c;
            float m02 = r00*r20*a + r01*r21*b + r02*r22*c;
            float m11 = r10*r10*a + r11*r11*b + r12*r12*c;
            float m12 = r10*r20*a + r11*r21*b + r12*r22*c;
            float m22 = r20*r20*a + r21*r21*b + r22*r22*c;

            float* o = s_out + 9*lt;    // stride-9 LDS: 2 lanes/bank, free
            o[0] = m00; o[1] = m01; o[2] = m02;
            o[3] = m01; o[4] = m11; o[5] = m12;
            o[6] = m02; o[7] = m12; o[8] = m22;
        }
    }
    __syncthreads();

    // ---- cooperative coalesced nt-store flush (2304 fvec4 / block) ----
    {
        const long long obase4 = (long long)blockIdx.x * (TILE * 9 / 4);
        const long long otot4  = (9LL * n) / 4;
        #pragma unroll
        for (int j = t; j < TILE * 9 / 4; j += BLOCK) {
            long long go = obase4 + (long long)j;
            if (go < otot4)
                __builtin_nontemporal_store(((fvec4*)s_out)[j], &out4[go]);
        }
    }
}

extern "C" void kernel_launch(void* const* d_in, const int* in_sizes, int n_in,
                              void* d_out, int out_size, void* d_ws, size_t ws_size,
                              hipStream_t stream) {
    const fvec4* quat   = (const fvec4*)d_in[0];
    const fvec4* scale4 = (const fvec4*)d_in[1];
    fvec4* out4 = (fvec4*)d_out;
    int n = in_sizes[0] / 4;   // quaternion is (N,4)

    int grid = (n + TILE - 1) / TILE;
    gaussians_cov_kernel<<<grid, BLOCK, 0, stream>>>(quat, scale4, out4, n);
}